// Round 1
// baseline (12787.559 us; speedup 1.0000x reference)
//
#include <hip/hip_runtime.h>
#include <stdint.h>

#define Bsz 256
#define Tsz 512
#define Isz 512
#define Hsz 1024

typedef __attribute__((ext_vector_type(8))) short short8;
typedef __attribute__((ext_vector_type(4))) float f32x4;

// ws layout (footprint unchanged from previous version)
static constexpr size_t XBF_OFF  = 0;                    // x bf16 [T][B][I]   = 128 MB
static constexpr size_t WIBF_OFF = 134217728;            // W_ih bf16 [4096][512] = 4 MB
static constexpr size_t HBUF_OFF = 138412032;            // h double buf bf16 [2][B][H] = 1 MB
static constexpr size_t FLAG_OFF = 139460608;            // 1024 per-wave slots, 32 B apart = 32 KB
static constexpr size_t WS_NEED  = 139493376;

__device__ __forceinline__ unsigned short f2bf(float f) {
  union { float f; unsigned u; } v; v.f = f;
  unsigned r = v.u + 0x7fff + ((v.u >> 16) & 1);   // RNE
  return (unsigned short)(r >> 16);
}

__device__ __forceinline__ void cvt8(const float* __restrict__ s, unsigned short* __restrict__ d) {
  float4 a = *(const float4*)s;
  float4 b = *(const float4*)(s + 4);
  union { unsigned short us[8]; uint4 v; } o;
  o.us[0] = f2bf(a.x); o.us[1] = f2bf(a.y); o.us[2] = f2bf(a.z); o.us[3] = f2bf(a.w);
  o.us[4] = f2bf(b.x); o.us[5] = f2bf(b.y); o.us[6] = f2bf(b.z); o.us[7] = f2bf(b.w);
  *(uint4*)d = o.v;
}

// L2-bypassing h-fragment load: two 8-byte relaxed agent-scope atomic loads
// (sc1 -> served fresh from the coherent memory-side LLC; no buffer_inv).
__device__ __forceinline__ short8 ld_h(const unsigned short* p) {
  unsigned long long lo = __hip_atomic_load((unsigned long long*)(void*)p,
                                            __ATOMIC_RELAXED, __HIP_MEMORY_SCOPE_AGENT);
  unsigned long long hi = __hip_atomic_load((unsigned long long*)(void*)(p + 4),
                                            __ATOMIC_RELAXED, __HIP_MEMORY_SCOPE_AGENT);
  union { unsigned long long q[2]; short8 s; } u;
  u.q[0] = lo; u.q[1] = hi;
  return u.s;
}

__device__ __forceinline__ unsigned ld_flag(const unsigned* p) {
  return __hip_atomic_load((unsigned*)p, __ATOMIC_RELAXED, __HIP_MEMORY_SCOPE_AGENT);
}

// ---------------------------------------------------------------------------
// Init: x [B][T][I] fp32 -> xbf [T][B][I] bf16 ; W_ih fp32 -> bf16 ; zero h/flags
// ---------------------------------------------------------------------------
__global__ __launch_bounds__(256)
void init_kernel(const float* __restrict__ x, const float* __restrict__ Wi,
                 unsigned char* __restrict__ ws)
{
  unsigned short* xbf  = (unsigned short*)(ws + XBF_OFF);
  unsigned short* wibf = (unsigned short*)(ws + WIBF_OFF);
  const int bid = blockIdx.x;
  const int tid = threadIdx.x;

  if (bid < 32768) {
    const int rowid = bid * 4 + (tid >> 6);      // rowid = t*256 + b
    const int t = rowid >> 8;
    const int b = rowid & 255;
    const int i = (tid & 63) * 8;
    const float* src = x + ((size_t)b * Tsz + t) * Isz + i;
    unsigned short* dst = xbf + (size_t)rowid * Isz + i;
    cvt8(src, dst);
  } else if (bid < 32768 + 1024) {
    const size_t base = (size_t)(bid - 32768) * 2048 + (size_t)tid * 8;
    cvt8(Wi + base, wibf + base);
  } else {
    // zero h_buf (1 MB) + flags (32 KB) = 67584 x 16B chunks
    const int z = bid - 33792;                    // 0..259
    uint4 zero = make_uint4(0u, 0u, 0u, 0u);
    for (size_t j = (size_t)z * 256 + tid; j < 67584; j += (size_t)260 * 256)
      ((uint4*)(ws + HBUF_OFF))[j] = zero;
  }
}

// ---------------------------------------------------------------------------
// Persistent LSTM: 256 WGs (4 row-groups x 64 hidden-groups), 256 threads.
// Sync rework: per-producer-WAVE flags (store-based arrive, no RMW, no
// global barrier, no per-step __syncthreads). Wave (rg,cg,wv) exchanges h
// only with waves (rg,*,wv) -> 4x64 independent 64-wave rings. Consumption
// is chunk-gated just-in-time inside the K-loop, so producer skew pipelines
// instead of accumulating into a grid-wide max.
// ---------------------------------------------------------------------------
__global__ __launch_bounds__(256, 1)
void lstm_persistent(const float* __restrict__ Wh,
                     const float* __restrict__ b_ih, const float* __restrict__ b_hh,
                     const float* __restrict__ c0, float* __restrict__ out,
                     unsigned char* __restrict__ ws)
{
  const unsigned short* __restrict__ xbf  = (const unsigned short*)(ws + XBF_OFF);
  const unsigned short* __restrict__ wibf = (const unsigned short*)(ws + WIBF_OFF);
  unsigned short* __restrict__ hbuf = (unsigned short*)(ws + HBUF_OFF);
  unsigned* __restrict__ flags = (unsigned*)(ws + FLAG_OFF);

  __shared__ unsigned short WhT[64][1032];   // +8 pad: 2-way LDS aliasing (free)
  __shared__ float bias[64];

  const int tid  = threadIdx.x;
  const int bid  = blockIdx.x;
  const int cg   = bid & 63;
  const int rg   = bid >> 6;
  const int wv   = tid >> 6;
  const int lane = tid & 63;
  const int l16  = lane & 15;
  const int quad = lane >> 4;

  // ---- stage W_hh slice (fp32 -> bf16) into LDS ----
  {
    const int n  = tid >> 2;
    const int q  = n >> 4, u = n & 15;
    const int gc = q * 1024 + cg * 16 + u;
    const int k0 = (tid & 3) * 256;
    const float* src = Wh + (size_t)gc * Hsz + k0;
    unsigned short* dst = &WhT[n][k0];
    #pragma unroll 4
    for (int k = 0; k < 256; k += 8) cvt8(src + k, dst + k);
  }
  if (tid < 64) {
    const int q = tid >> 4, u = tid & 15;
    const int gc = q * 1024 + cg * 16 + u;
    bias[tid] = b_ih[gc] + b_hh[gc];
  }
  __syncthreads();

  const int rowbase = rg * 64 + wv * 16;
  const int arow    = rowbase + l16;
  const int hcol    = cg * 16 + l16;

  // flag slot layout: uint index ((rg*64 + c)*4 + wv) * 8  (32 B apart, 32 KB total)
  unsigned* const flag_base = flags + (size_t)rg * 2048 + (size_t)wv * 8; // c = 0
  unsigned* const myslot    = flag_base + (size_t)cg * 32;
  unsigned* const poll16    = flag_base + (size_t)l16 * 32;   // lanes poll producers 0..15

  // loop-invariant biases in registers
  const float bi_r = bias[l16];
  const float bf_r = bias[16 + l16];
  const float bg_r = bias[32 + l16];
  const float bo_r = bias[48 + l16];

  float creg[4];
  #pragma unroll
  for (int r = 0; r < 4; ++r)
    creg[r] = c0[(size_t)(rowbase + quad * 4 + r) * Hsz + hcol];

  const unsigned short* bp[4];
  #pragma unroll
  for (int q = 0; q < 4; ++q)
    bp[q] = wibf + (size_t)(q * 1024 + cg * 16 + l16) * Isz + quad * 8;

  int p = 0;
  for (int t = 0; t < Tsz; ++t) {
    const unsigned short* xt = xbf  + (size_t)t * Bsz * Isz + (size_t)arow * Isz + quad * 8;
    const unsigned short* hp = hbuf + (size_t)p * Bsz * Hsz + (size_t)arow * Hsz + quad * 8;
    const unsigned tgt = (unsigned)t;

    f32x4 acc[4];
    #pragma unroll
    for (int q = 0; q < 4; ++q) acc[q] = (f32x4){0.f, 0.f, 0.f, 0.f};

    // ---- x @ W_ih^T partial (no h dependency -> overlaps producer skew) ----
    #pragma unroll 4
    for (int ks = 0; ks < 16; ++ks) {
      const int kk = ks * 32;
      short8 av = *(const short8*)(xt + kk);
      short8 b0 = *(const short8*)(bp[0] + kk);
      short8 b1 = *(const short8*)(bp[1] + kk);
      short8 b2 = *(const short8*)(bp[2] + kk);
      short8 b3 = *(const short8*)(bp[3] + kk);
      acc[0] = __builtin_amdgcn_mfma_f32_16x16x32_bf16(av, b0, acc[0], 0, 0, 0);
      acc[1] = __builtin_amdgcn_mfma_f32_16x16x32_bf16(av, b1, acc[1], 0, 0, 0);
      acc[2] = __builtin_amdgcn_mfma_f32_16x16x32_bf16(av, b2, acc[2], 0, 0, 0);
      acc[3] = __builtin_amdgcn_mfma_f32_16x16x32_bf16(av, b3, acc[3], 0, 0, 0);
    }

    // ---- gate the initial depth-8 prefetch on producers 0..15 (this wv ring) ----
    if (t > 0) {
      unsigned v = ld_flag(poll16);
      while (!__all((int)(v >= tgt))) v = ld_flag(poll16);
      __atomic_signal_fence(__ATOMIC_SEQ_CST);   // keep data loads after flag obs
    }

    short8 hv[8];
    #pragma unroll
    for (int j = 0; j < 8; ++j) hv[j] = ld_h(hp + j * 32);

    // ---- h @ W_hh^T, depth-8 ILP prefetch; each prefetch JIT-gated on its
    //      two producer waves (broadcast same-address flag loads). By loop end
    //      all 64 peer flags >= t observed -> epilogue WAR-safe. ----
    #pragma unroll
    for (int ks = 0; ks < 32; ++ks) {
      short8 av = hv[ks & 7];
      const int kk = ks * 32;
      short8 b0 = *(const short8*)(&WhT[l16     ][kk + quad * 8]);
      short8 b1 = *(const short8*)(&WhT[16 + l16][kk + quad * 8]);
      short8 b2 = *(const short8*)(&WhT[32 + l16][kk + quad * 8]);
      short8 b3 = *(const short8*)(&WhT[48 + l16][kk + quad * 8]);
      acc[0] = __builtin_amdgcn_mfma_f32_16x16x32_bf16(av, b0, acc[0], 0, 0, 0);
      acc[1] = __builtin_amdgcn_mfma_f32_16x16x32_bf16(av, b1, acc[1], 0, 0, 0);
      acc[2] = __builtin_amdgcn_mfma_f32_16x16x32_bf16(av, b2, acc[2], 0, 0, 0);
      acc[3] = __builtin_amdgcn_mfma_f32_16x16x32_bf16(av, b3, acc[3], 0, 0, 0);
      if (ks < 24) {
        if (t > 0) {
          unsigned* pa = flag_base + (size_t)(2 * (ks + 8)) * 32;
          unsigned* pb = pa + 32;
          unsigned va = ld_flag(pa);
          unsigned vb = ld_flag(pb);
          while (va < tgt || vb < tgt) { va = ld_flag(pa); vb = ld_flag(pb); }
          __atomic_signal_fence(__ATOMIC_SEQ_CST);
        }
        hv[ks & 7] = ld_h(hp + (ks + 8) * 32);
      }
    }

    // ---- epilogue: gates -> c,h; h published via sc1 (LLC) atomic stores ----
    unsigned short* hn = hbuf + (size_t)(p ^ 1) * Bsz * Hsz;
    #pragma unroll
    for (int r = 0; r < 4; ++r) {
      float gi = acc[0][r] + bi_r;
      float gf = acc[1][r] + bf_r;
      float gg = acc[2][r] + bg_r;
      float go = acc[3][r] + bo_r;
      float si = 1.f / (1.f + __expf(-gi));
      float sf = 1.f / (1.f + __expf(-gf));
      float tg = 1.f - 2.f / (__expf(2.f * gg) + 1.f);
      float so = 1.f / (1.f + __expf(-go));
      float cn = sf * creg[r] + si * tg;
      creg[r] = cn;
      float tc = 1.f - 2.f / (__expf(2.f * cn) + 1.f);
      __hip_atomic_store(&hn[(size_t)(rowbase + quad * 4 + r) * Hsz + hcol],
                         f2bf(so * tc), __ATOMIC_RELAXED, __HIP_MEMORY_SCOPE_AGENT);
    }

    // ---- arrive: per-wave. Drain own sc1 stores (ACKed at LLC), then one
    // plain relaxed flag STORE (no RMW, no serialization, no __syncthreads).
    asm volatile("s_waitcnt vmcnt(0)" ::: "memory");
    if (lane == 0)
      __hip_atomic_store(myslot, tgt + 1u, __ATOMIC_RELAXED, __HIP_MEMORY_SCOPE_AGENT);
    p ^= 1;
  }

  #pragma unroll
  for (int r = 0; r < 4; ++r)
    out[(size_t)(rowbase + quad * 4 + r) * Hsz + hcol] = creg[r];
}

extern "C" void kernel_launch(void* const* d_in, const int* in_sizes, int n_in,
                              void* d_out, int out_size, void* d_ws, size_t ws_size,
                              hipStream_t stream) {
  const float* x   = (const float*)d_in[0];
  const float* Wi  = (const float*)d_in[1];
  const float* Wh  = (const float*)d_in[2];
  const float* bih = (const float*)d_in[3];
  const float* bhh = (const float*)d_in[4];
  const float* c0  = (const float*)d_in[5];
  float* out = (float*)d_out;
  unsigned char* ws = (unsigned char*)d_ws;

  if (ws_size < WS_NEED) return;

  init_kernel<<<34052, 256, 0, stream>>>(x, Wi, ws);

  void* args[] = { (void*)&Wh, (void*)&bih, (void*)&bhh,
                   (void*)&c0, (void*)&out, (void*)&ws };
  hipLaunchCooperativeKernel((void*)lstm_persistent, dim3(256), dim3(256),
                             args, 0, stream);
}

// Round 2
// 9934.429 us; speedup vs baseline: 1.2872x; 1.2872x over previous
//
#include <hip/hip_runtime.h>
#include <stdint.h>

#define Bsz 256
#define Tsz 512
#define Isz 512
#define Hsz 1024

typedef __attribute__((ext_vector_type(8))) short short8;
typedef __attribute__((ext_vector_type(4))) float f32x4;

// ws layout (footprint unchanged)
static constexpr size_t XBF_OFF  = 0;                    // x bf16 [T][B][I]   = 128 MB
static constexpr size_t WIBF_OFF = 134217728;            // W_ih bf16 [4096][512] = 4 MB
static constexpr size_t HBUF_OFF = 138412032;            // h double buf bf16 [2][B][H] = 1 MB
static constexpr size_t FLAG_OFF = 139460608;            // 1024 per-wave slots, 32 B apart = 32 KB
static constexpr size_t WS_NEED  = 139493376;

__device__ __forceinline__ unsigned short f2bf(float f) {
  union { float f; unsigned u; } v; v.f = f;
  unsigned r = v.u + 0x7fff + ((v.u >> 16) & 1);   // RNE
  return (unsigned short)(r >> 16);
}

__device__ __forceinline__ void cvt8(const float* __restrict__ s, unsigned short* __restrict__ d) {
  float4 a = *(const float4*)s;
  float4 b = *(const float4*)(s + 4);
  union { unsigned short us[8]; uint4 v; } o;
  o.us[0] = f2bf(a.x); o.us[1] = f2bf(a.y); o.us[2] = f2bf(a.z); o.us[3] = f2bf(a.w);
  o.us[4] = f2bf(b.x); o.us[5] = f2bf(b.y); o.us[6] = f2bf(b.z); o.us[7] = f2bf(b.w);
  *(uint4*)d = o.v;
}

// L2-bypassing h-fragment load: two 8-byte relaxed agent-scope atomic loads
// (sc1 -> served fresh from the coherent memory-side LLC; no buffer_inv).
__device__ __forceinline__ short8 ld_h(const unsigned short* p) {
  unsigned long long lo = __hip_atomic_load((unsigned long long*)(void*)p,
                                            __ATOMIC_RELAXED, __HIP_MEMORY_SCOPE_AGENT);
  unsigned long long hi = __hip_atomic_load((unsigned long long*)(void*)(p + 4),
                                            __ATOMIC_RELAXED, __HIP_MEMORY_SCOPE_AGENT);
  union { unsigned long long q[2]; short8 s; } u;
  u.q[0] = lo; u.q[1] = hi;
  return u.s;
}

__device__ __forceinline__ unsigned ld_flag(const unsigned* p) {
  return __hip_atomic_load((unsigned*)p, __ATOMIC_RELAXED, __HIP_MEMORY_SCOPE_AGENT);
}

// ---------------------------------------------------------------------------
// Init: x [B][T][I] fp32 -> xbf [T][B][I] bf16 ; W_ih fp32 -> bf16 ; zero h/flags
// ---------------------------------------------------------------------------
__global__ __launch_bounds__(256)
void init_kernel(const float* __restrict__ x, const float* __restrict__ Wi,
                 unsigned char* __restrict__ ws)
{
  unsigned short* xbf  = (unsigned short*)(ws + XBF_OFF);
  unsigned short* wibf = (unsigned short*)(ws + WIBF_OFF);
  const int bid = blockIdx.x;
  const int tid = threadIdx.x;

  if (bid < 32768) {
    const int rowid = bid * 4 + (tid >> 6);      // rowid = t*256 + b
    const int t = rowid >> 8;
    const int b = rowid & 255;
    const int i = (tid & 63) * 8;
    const float* src = x + ((size_t)b * Tsz + t) * Isz + i;
    unsigned short* dst = xbf + (size_t)rowid * Isz + i;
    cvt8(src, dst);
  } else if (bid < 32768 + 1024) {
    const size_t base = (size_t)(bid - 32768) * 2048 + (size_t)tid * 8;
    cvt8(Wi + base, wibf + base);
  } else {
    // zero h_buf (1 MB) + flags (32 KB) = 67584 x 16B chunks
    const int z = bid - 33792;                    // 0..259
    uint4 zero = make_uint4(0u, 0u, 0u, 0u);
    for (size_t j = (size_t)z * 256 + tid; j < 67584; j += (size_t)260 * 256)
      ((uint4*)(ws + HBUF_OFF))[j] = zero;
  }
}

// ---------------------------------------------------------------------------
// Persistent LSTM: 256 WGs (4 row-groups x 64 hidden-groups), 256 threads.
// Sync: per-producer-WAVE flags, store-based arrive (no RMW, no per-step
// __syncthreads). ONE up-front wait per step: a single 64-lane vector load
// polls all 64 ring producers (lane i <- producer cg=i). No flag polls inside
// the K-loop (vmcnt completion is in-order: any interior poll would drain the
// h prefetch pipeline -- round-1 lesson). h prefetch deepened to 16.
// ---------------------------------------------------------------------------
__global__ __launch_bounds__(256, 1)
void lstm_persistent(const float* __restrict__ Wh,
                     const float* __restrict__ b_ih, const float* __restrict__ b_hh,
                     const float* __restrict__ c0, float* __restrict__ out,
                     unsigned char* __restrict__ ws)
{
  const unsigned short* __restrict__ xbf  = (const unsigned short*)(ws + XBF_OFF);
  const unsigned short* __restrict__ wibf = (const unsigned short*)(ws + WIBF_OFF);
  unsigned short* __restrict__ hbuf = (unsigned short*)(ws + HBUF_OFF);
  unsigned* __restrict__ flags = (unsigned*)(ws + FLAG_OFF);

  __shared__ unsigned short WhT[64][1032];   // +8 pad: 2-way LDS aliasing (free)
  __shared__ float bias[64];

  const int tid  = threadIdx.x;
  const int bid  = blockIdx.x;
  const int cg   = bid & 63;
  const int rg   = bid >> 6;
  const int wv   = tid >> 6;
  const int lane = tid & 63;
  const int l16  = lane & 15;
  const int quad = lane >> 4;

  // ---- stage W_hh slice (fp32 -> bf16) into LDS ----
  {
    const int n  = tid >> 2;
    const int q  = n >> 4, u = n & 15;
    const int gc = q * 1024 + cg * 16 + u;
    const int k0 = (tid & 3) * 256;
    const float* src = Wh + (size_t)gc * Hsz + k0;
    unsigned short* dst = &WhT[n][k0];
    #pragma unroll 4
    for (int k = 0; k < 256; k += 8) cvt8(src + k, dst + k);
  }
  if (tid < 64) {
    const int q = tid >> 4, u = tid & 15;
    const int gc = q * 1024 + cg * 16 + u;
    bias[tid] = b_ih[gc] + b_hh[gc];
  }
  __syncthreads();

  const int rowbase = rg * 64 + wv * 16;
  const int arow    = rowbase + l16;
  const int hcol    = cg * 16 + l16;

  // flag slot layout: uint index ((rg*64 + c)*4 + wv) * 8  (32 B apart, 32 KB)
  unsigned* const flag_base = flags + (size_t)rg * 2048 + (size_t)wv * 8; // c = 0
  unsigned* const myslot    = flag_base + (size_t)cg * 32;
  unsigned* const pollp     = flag_base + (size_t)lane * 32;  // lane i -> producer cg=i

  // loop-invariant biases in registers
  const float bi_r = bias[l16];
  const float bf_r = bias[16 + l16];
  const float bg_r = bias[32 + l16];
  const float bo_r = bias[48 + l16];

  float creg[4];
  #pragma unroll
  for (int r = 0; r < 4; ++r)
    creg[r] = c0[(size_t)(rowbase + quad * 4 + r) * Hsz + hcol];

  const unsigned short* bp[4];
  #pragma unroll
  for (int q = 0; q < 4; ++q)
    bp[q] = wibf + (size_t)(q * 1024 + cg * 16 + l16) * Isz + quad * 8;

  int p = 0;
  for (int t = 0; t < Tsz; ++t) {
    const unsigned short* xt = xbf  + (size_t)t * Bsz * Isz + (size_t)arow * Isz + quad * 8;
    const unsigned short* hp = hbuf + (size_t)p * Bsz * Hsz + (size_t)arow * Hsz + quad * 8;
    const unsigned tgt = (unsigned)t;

    f32x4 acc[4];
    #pragma unroll
    for (int q = 0; q < 4; ++q) acc[q] = (f32x4){0.f, 0.f, 0.f, 0.f};

    // ---- x @ W_ih^T partial (no h dependency -> absorbs producer skew) ----
    #pragma unroll 4
    for (int ks = 0; ks < 16; ++ks) {
      const int kk = ks * 32;
      short8 av = *(const short8*)(xt + kk);
      short8 b0 = *(const short8*)(bp[0] + kk);
      short8 b1 = *(const short8*)(bp[1] + kk);
      short8 b2 = *(const short8*)(bp[2] + kk);
      short8 b3 = *(const short8*)(bp[3] + kk);
      acc[0] = __builtin_amdgcn_mfma_f32_16x16x32_bf16(av, b0, acc[0], 0, 0, 0);
      acc[1] = __builtin_amdgcn_mfma_f32_16x16x32_bf16(av, b1, acc[1], 0, 0, 0);
      acc[2] = __builtin_amdgcn_mfma_f32_16x16x32_bf16(av, b2, acc[2], 0, 0, 0);
      acc[3] = __builtin_amdgcn_mfma_f32_16x16x32_bf16(av, b3, acc[3], 0, 0, 0);
    }

    // ---- single wait: one 64-lane load covers all 64 ring producers ----
    if (t > 0) {
      unsigned v = ld_flag(pollp);
      while (!__all((int)(v >= tgt))) v = ld_flag(pollp);
      __atomic_signal_fence(__ATOMIC_SEQ_CST);   // keep data loads after flag obs
    }

    // ---- h @ W_hh^T, depth-16 ILP prefetch on the LLC h loads ----
    short8 hv[16];
    #pragma unroll
    for (int j = 0; j < 16; ++j) hv[j] = ld_h(hp + j * 32);

    #pragma unroll
    for (int ks = 0; ks < 32; ++ks) {
      short8 av = hv[ks & 15];
      if (ks + 16 < 32) hv[ks & 15] = ld_h(hp + (ks + 16) * 32);
      const int kk = ks * 32;
      short8 b0 = *(const short8*)(&WhT[l16     ][kk + quad * 8]);
      short8 b1 = *(const short8*)(&WhT[16 + l16][kk + quad * 8]);
      short8 b2 = *(const short8*)(&WhT[32 + l16][kk + quad * 8]);
      short8 b3 = *(const short8*)(&WhT[48 + l16][kk + quad * 8]);
      acc[0] = __builtin_amdgcn_mfma_f32_16x16x32_bf16(av, b0, acc[0], 0, 0, 0);
      acc[1] = __builtin_amdgcn_mfma_f32_16x16x32_bf16(av, b1, acc[1], 0, 0, 0);
      acc[2] = __builtin_amdgcn_mfma_f32_16x16x32_bf16(av, b2, acc[2], 0, 0, 0);
      acc[3] = __builtin_amdgcn_mfma_f32_16x16x32_bf16(av, b3, acc[3], 0, 0, 0);
    }

    // ---- epilogue: gates -> c,h; h published via sc1 (LLC) atomic stores ----
    unsigned short* hn = hbuf + (size_t)(p ^ 1) * Bsz * Hsz;
    #pragma unroll
    for (int r = 0; r < 4; ++r) {
      float gi = acc[0][r] + bi_r;
      float gf = acc[1][r] + bf_r;
      float gg = acc[2][r] + bg_r;
      float go = acc[3][r] + bo_r;
      float si = 1.f / (1.f + __expf(-gi));
      float sf = 1.f / (1.f + __expf(-gf));
      float tg = 1.f - 2.f / (__expf(2.f * gg) + 1.f);
      float so = 1.f / (1.f + __expf(-go));
      float cn = sf * creg[r] + si * tg;
      creg[r] = cn;
      float tc = 1.f - 2.f / (__expf(2.f * cn) + 1.f);
      __hip_atomic_store(&hn[(size_t)(rowbase + quad * 4 + r) * Hsz + hcol],
                         f2bf(so * tc), __ATOMIC_RELAXED, __HIP_MEMORY_SCOPE_AGENT);
    }

    // ---- arrive: per-wave. Drain own sc1 stores (ACKed at LLC), then one
    // plain relaxed flag STORE (no RMW, no serialization, no __syncthreads).
    asm volatile("s_waitcnt vmcnt(0)" ::: "memory");
    if (lane == 0)
      __hip_atomic_store(myslot, tgt + 1u, __ATOMIC_RELAXED, __HIP_MEMORY_SCOPE_AGENT);
    p ^= 1;
  }

  #pragma unroll
  for (int r = 0; r < 4; ++r)
    out[(size_t)(rowbase + quad * 4 + r) * Hsz + hcol] = creg[r];
}

extern "C" void kernel_launch(void* const* d_in, const int* in_sizes, int n_in,
                              void* d_out, int out_size, void* d_ws, size_t ws_size,
                              hipStream_t stream) {
  const float* x   = (const float*)d_in[0];
  const float* Wi  = (const float*)d_in[1];
  const float* Wh  = (const float*)d_in[2];
  const float* bih = (const float*)d_in[3];
  const float* bhh = (const float*)d_in[4];
  const float* c0  = (const float*)d_in[5];
  float* out = (float*)d_out;
  unsigned char* ws = (unsigned char*)d_ws;

  if (ws_size < WS_NEED) return;

  init_kernel<<<34052, 256, 0, stream>>>(x, Wi, ws);

  void* args[] = { (void*)&Wh, (void*)&bih, (void*)&bhh,
                   (void*)&c0, (void*)&out, (void*)&ws };
  hipLaunchCooperativeKernel((void*)lstm_persistent, dim3(256), dim3(256),
                             args, 0, stream);
}

// Round 3
// 9158.466 us; speedup vs baseline: 1.3963x; 1.0847x over previous
//
#include <hip/hip_runtime.h>
#include <stdint.h>

#define Bsz 256
#define Tsz 512
#define Isz 512
#define Hsz 1024

typedef __attribute__((ext_vector_type(8))) short short8;
typedef __attribute__((ext_vector_type(4))) float f32x4;

// ws layout (footprint unchanged)
static constexpr size_t XBF_OFF  = 0;                    // x bf16 [T][B][I]   = 128 MB
static constexpr size_t WIBF_OFF = 134217728;            // W_ih bf16 [4096][512] = 4 MB
static constexpr size_t HBUF_OFF = 138412032;            // h double buf bf16 [2][B][H] = 1 MB
static constexpr size_t FLAG_OFF = 139460608;            // per-(rg,cg,wv4) slots, 32 B apart
static constexpr size_t WS_NEED  = 139493376;

__device__ __forceinline__ unsigned short f2bf(float f) {
  union { float f; unsigned u; } v; v.f = f;
  unsigned r = v.u + 0x7fff + ((v.u >> 16) & 1);   // RNE
  return (unsigned short)(r >> 16);
}

__device__ __forceinline__ void cvt8(const float* __restrict__ s, unsigned short* __restrict__ d) {
  float4 a = *(const float4*)s;
  float4 b = *(const float4*)(s + 4);
  union { unsigned short us[8]; uint4 v; } o;
  o.us[0] = f2bf(a.x); o.us[1] = f2bf(a.y); o.us[2] = f2bf(a.z); o.us[3] = f2bf(a.w);
  o.us[4] = f2bf(b.x); o.us[5] = f2bf(b.y); o.us[6] = f2bf(b.z); o.us[7] = f2bf(b.w);
  *(uint4*)d = o.v;
}

// L2-bypassing h-fragment load: two 8-byte relaxed agent-scope atomic loads
// (sc1 -> served fresh from the coherent memory-side LLC; no buffer_inv).
__device__ __forceinline__ short8 ld_h(const unsigned short* p) {
  unsigned long long lo = __hip_atomic_load((unsigned long long*)(void*)p,
                                            __ATOMIC_RELAXED, __HIP_MEMORY_SCOPE_AGENT);
  unsigned long long hi = __hip_atomic_load((unsigned long long*)(void*)(p + 4),
                                            __ATOMIC_RELAXED, __HIP_MEMORY_SCOPE_AGENT);
  union { unsigned long long q[2]; short8 s; } u;
  u.q[0] = lo; u.q[1] = hi;
  return u.s;
}

__device__ __forceinline__ unsigned ld_flag(const unsigned* p) {
  return __hip_atomic_load((unsigned*)p, __ATOMIC_RELAXED, __HIP_MEMORY_SCOPE_AGENT);
}

// ---------------------------------------------------------------------------
// Init: x [B][T][I] fp32 -> xbf [T][B][I] bf16 ; W_ih fp32 -> bf16 ; zero h/flags
// ---------------------------------------------------------------------------
__global__ __launch_bounds__(256)
void init_kernel(const float* __restrict__ x, const float* __restrict__ Wi,
                 unsigned char* __restrict__ ws)
{
  unsigned short* xbf  = (unsigned short*)(ws + XBF_OFF);
  unsigned short* wibf = (unsigned short*)(ws + WIBF_OFF);
  const int bid = blockIdx.x;
  const int tid = threadIdx.x;

  if (bid < 32768) {
    const int rowid = bid * 4 + (tid >> 6);      // rowid = t*256 + b
    const int t = rowid >> 8;
    const int b = rowid & 255;
    const int i = (tid & 63) * 8;
    const float* src = x + ((size_t)b * Tsz + t) * Isz + i;
    unsigned short* dst = xbf + (size_t)rowid * Isz + i;
    cvt8(src, dst);
  } else if (bid < 32768 + 1024) {
    const size_t base = (size_t)(bid - 32768) * 2048 + (size_t)tid * 8;
    cvt8(Wi + base, wibf + base);
  } else {
    // zero h_buf (1 MB) + flags (32 KB) = 67584 x 16B chunks
    const int z = bid - 33792;                    // 0..259
    uint4 zero = make_uint4(0u, 0u, 0u, 0u);
    for (size_t j = (size_t)z * 256 + tid; j < 67584; j += (size_t)260 * 256)
      ((uint4*)(ws + HBUF_OFF))[j] = zero;
  }
}

// ---------------------------------------------------------------------------
// Persistent LSTM: 256 WGs x 512 threads (8 waves = 2/SIMD).
// K-split wave pairs: waves (wv, wv+4) compute the SAME 16row x 64gate-col
// tile over disjoint K halves (h cols 0..511 / 512..1023), reduced via LDS.
// Per-wave serial chain halves; SIMD hosts 2 waves -> stalls interleave.
// Total LLC h traffic unchanged. Sync: per-(rg,cg,wv4) flags, store-based
// arrive by the lower wave after the reduction barrier (which certifies the
// whole block's step-t reads drained -> WAR-safe). Each wave polls only the
// 32 producers of its own K half.
// ---------------------------------------------------------------------------
__global__ __launch_bounds__(512, 2)
void lstm_persistent(const float* __restrict__ Wh,
                     const float* __restrict__ b_ih, const float* __restrict__ b_hh,
                     const float* __restrict__ c0, float* __restrict__ out,
                     unsigned char* __restrict__ ws)
{
  const unsigned short* __restrict__ xbf  = (const unsigned short*)(ws + XBF_OFF);
  const unsigned short* __restrict__ wibf = (const unsigned short*)(ws + WIBF_OFF);
  unsigned short* __restrict__ hbuf = (unsigned short*)(ws + HBUF_OFF);
  unsigned* __restrict__ flags = (unsigned*)(ws + FLAG_OFF);

  __shared__ unsigned short WhT[64][1032];   // +8 pad: 2-way LDS aliasing (free)
  __shared__ float red[4][64][17];           // K-split partials; 17-pad: conflict-free
  __shared__ float bias[64];

  const int tid  = threadIdx.x;
  const int bid  = blockIdx.x;
  const int cg   = bid & 63;
  const int rg   = bid >> 6;
  const int wv    = tid >> 6;        // 0..7
  const int wv4   = wv & 3;          // row-slab index within block
  const int khalf = wv >> 2;         // 0: K 0..511, 1: K 512..1023
  const int lane = tid & 63;
  const int l16  = lane & 15;
  const int quad = lane >> 4;

  // ---- stage W_hh slice (fp32 -> bf16) into LDS (512 threads) ----
  {
    const int n  = tid >> 3;                 // 0..63
    const int q  = n >> 4, u = n & 15;
    const int gc = q * 1024 + cg * 16 + u;
    const int k0 = (tid & 7) * 128;
    const float* src = Wh + (size_t)gc * Hsz + k0;
    unsigned short* dst = &WhT[n][k0];
    #pragma unroll 4
    for (int k = 0; k < 128; k += 8) cvt8(src + k, dst + k);
  }
  if (tid < 64) {
    const int q = tid >> 4, u = tid & 15;
    const int gc = q * 1024 + cg * 16 + u;
    bias[tid] = b_ih[gc] + b_hh[gc];
  }
  __syncthreads();

  const int rowbase = rg * 64 + wv4 * 16;
  const int arow    = rowbase + l16;
  const int hcol    = cg * 16 + l16;

  // flag slot layout: uint index ((rg*64 + c)*4 + wv4) * 8  (32 B apart)
  unsigned* const flag_base = flags + (size_t)rg * 2048 + (size_t)wv4 * 8; // c = 0
  unsigned* const myslot    = flag_base + (size_t)cg * 32;
  // each wave polls only the 32 producers of its K half (lane&31 -> producer)
  unsigned* const pollp     = flag_base + (size_t)(khalf * 32 + (lane & 31)) * 32;

  // loop-invariant biases in registers (lower waves only use them)
  const float bi_r = bias[l16];
  const float bf_r = bias[16 + l16];
  const float bg_r = bias[32 + l16];
  const float bo_r = bias[48 + l16];

  float creg[4] = {0.f, 0.f, 0.f, 0.f};
  if (khalf == 0) {
    #pragma unroll
    for (int r = 0; r < 4; ++r)
      creg[r] = c0[(size_t)(rowbase + quad * 4 + r) * Hsz + hcol];
  }

  const unsigned short* bp[4];
  #pragma unroll
  for (int q = 0; q < 4; ++q)
    bp[q] = wibf + (size_t)(q * 1024 + cg * 16 + l16) * Isz + khalf * 256 + quad * 8;

  int p = 0;
  for (int t = 0; t < Tsz; ++t) {
    const unsigned short* xt = xbf  + (size_t)t * Bsz * Isz + (size_t)arow * Isz
                                    + khalf * 256 + quad * 8;
    const unsigned short* hp = hbuf + (size_t)p * Bsz * Hsz + (size_t)arow * Hsz
                                    + khalf * 512 + quad * 8;
    const unsigned tgt = (unsigned)t;

    f32x4 acc[4];
    #pragma unroll
    for (int q = 0; q < 4; ++q) acc[q] = (f32x4){0.f, 0.f, 0.f, 0.f};

    // ---- x @ W_ih^T partial, this wave's K quarter (no h dependency) ----
    #pragma unroll
    for (int ks = 0; ks < 8; ++ks) {
      const int kk = ks * 32;
      short8 av = *(const short8*)(xt + kk);
      short8 b0 = *(const short8*)(bp[0] + kk);
      short8 b1 = *(const short8*)(bp[1] + kk);
      short8 b2 = *(const short8*)(bp[2] + kk);
      short8 b3 = *(const short8*)(bp[3] + kk);
      acc[0] = __builtin_amdgcn_mfma_f32_16x16x32_bf16(av, b0, acc[0], 0, 0, 0);
      acc[1] = __builtin_amdgcn_mfma_f32_16x16x32_bf16(av, b1, acc[1], 0, 0, 0);
      acc[2] = __builtin_amdgcn_mfma_f32_16x16x32_bf16(av, b2, acc[2], 0, 0, 0);
      acc[3] = __builtin_amdgcn_mfma_f32_16x16x32_bf16(av, b3, acc[3], 0, 0, 0);
    }

    // ---- single wait on this K-half's 32 producers ----
    if (t > 0) {
      unsigned v = ld_flag(pollp);
      while (!__all((int)(v >= tgt))) v = ld_flag(pollp);
      __atomic_signal_fence(__ATOMIC_SEQ_CST);   // keep data loads after flag obs
    }

    // ---- h @ W_hh^T over this wave's 512-col K half, depth-8 prefetch ----
    short8 hv[8];
    #pragma unroll
    for (int j = 0; j < 8; ++j) hv[j] = ld_h(hp + j * 32);

    const int kbase = khalf * 512;
    #pragma unroll
    for (int ks = 0; ks < 16; ++ks) {
      short8 av = hv[ks & 7];
      if (ks + 8 < 16) hv[ks & 7] = ld_h(hp + (ks + 8) * 32);
      const int kk = kbase + ks * 32;
      short8 b0 = *(const short8*)(&WhT[l16     ][kk + quad * 8]);
      short8 b1 = *(const short8*)(&WhT[16 + l16][kk + quad * 8]);
      short8 b2 = *(const short8*)(&WhT[32 + l16][kk + quad * 8]);
      short8 b3 = *(const short8*)(&WhT[48 + l16][kk + quad * 8]);
      acc[0] = __builtin_amdgcn_mfma_f32_16x16x32_bf16(av, b0, acc[0], 0, 0, 0);
      acc[1] = __builtin_amdgcn_mfma_f32_16x16x32_bf16(av, b1, acc[1], 0, 0, 0);
      acc[2] = __builtin_amdgcn_mfma_f32_16x16x32_bf16(av, b2, acc[2], 0, 0, 0);
      acc[3] = __builtin_amdgcn_mfma_f32_16x16x32_bf16(av, b3, acc[3], 0, 0, 0);
    }

    // ---- K-split reduction through LDS ----
    if (khalf) {
      #pragma unroll
      for (int q = 0; q < 4; ++q)
        #pragma unroll
        for (int r = 0; r < 4; ++r)
          red[wv4][lane][q * 4 + r] = acc[q][r];
    }
    __syncthreads();                       // barrier1: partials visible; all
                                           // waves' step-t reads drained here
    if (!khalf) {
      #pragma unroll
      for (int q = 0; q < 4; ++q)
        #pragma unroll
        for (int r = 0; r < 4; ++r)
          acc[q][r] += red[wv4][lane][q * 4 + r];
    }
    __syncthreads();                       // barrier2: red reusable next step

    if (!khalf) {
      // ---- epilogue: gates -> c,h; h published via sc1 (LLC) stores ----
      unsigned short* hn = hbuf + (size_t)(p ^ 1) * Bsz * Hsz;
      #pragma unroll
      for (int r = 0; r < 4; ++r) {
        float gi = acc[0][r] + bi_r;
        float gf = acc[1][r] + bf_r;
        float gg = acc[2][r] + bg_r;
        float go = acc[3][r] + bo_r;
        float si = 1.f / (1.f + __expf(-gi));
        float sf = 1.f / (1.f + __expf(-gf));
        float tg = 1.f - 2.f / (__expf(2.f * gg) + 1.f);
        float so = 1.f / (1.f + __expf(-go));
        float cn = sf * creg[r] + si * tg;
        creg[r] = cn;
        float tc = 1.f - 2.f / (__expf(2.f * cn) + 1.f);
        __hip_atomic_store(&hn[(size_t)(rowbase + quad * 4 + r) * Hsz + hcol],
                           f2bf(so * tc), __ATOMIC_RELAXED, __HIP_MEMORY_SCOPE_AGENT);
      }

      // ---- arrive: drain own sc1 stores (ACKed at LLC), then one plain
      // relaxed flag STORE. Barrier1 already certified the upper wave's
      // step-t reads drained, so flag >= t+1 discharges the ring's WAR. ----
      asm volatile("s_waitcnt vmcnt(0)" ::: "memory");
      if (lane == 0)
        __hip_atomic_store(myslot, tgt + 1u, __ATOMIC_RELAXED, __HIP_MEMORY_SCOPE_AGENT);
    }
    p ^= 1;
  }

  if (khalf == 0) {
    #pragma unroll
    for (int r = 0; r < 4; ++r)
      out[(size_t)(rowbase + quad * 4 + r) * Hsz + hcol] = creg[r];
  }
}

extern "C" void kernel_launch(void* const* d_in, const int* in_sizes, int n_in,
                              void* d_out, int out_size, void* d_ws, size_t ws_size,
                              hipStream_t stream) {
  const float* x   = (const float*)d_in[0];
  const float* Wi  = (const float*)d_in[1];
  const float* Wh  = (const float*)d_in[2];
  const float* bih = (const float*)d_in[3];
  const float* bhh = (const float*)d_in[4];
  const float* c0  = (const float*)d_in[5];
  float* out = (float*)d_out;
  unsigned char* ws = (unsigned char*)d_ws;

  if (ws_size < WS_NEED) return;

  init_kernel<<<34052, 256, 0, stream>>>(x, Wi, ws);

  void* args[] = { (void*)&Wh, (void*)&bih, (void*)&bhh,
                   (void*)&c0, (void*)&out, (void*)&ws };
  hipLaunchCooperativeKernel((void*)lstm_persistent, dim3(256), dim3(512),
                             args, 0, stream);
}

// Round 4
// 9025.742 us; speedup vs baseline: 1.4168x; 1.0147x over previous
//
#include <hip/hip_runtime.h>
#include <stdint.h>

#define Bsz 256
#define Tsz 512
#define Isz 512
#define Hsz 1024

typedef __attribute__((ext_vector_type(8))) short short8;
typedef __attribute__((ext_vector_type(4))) float f32x4;

// ws layout (footprint unchanged)
static constexpr size_t XBF_OFF  = 0;                    // x bf16 [T][B][I]   = 128 MB
static constexpr size_t WIBF_OFF = 134217728;            // W_ih bf16 [4096][512] = 4 MB
static constexpr size_t HBUF_OFF = 138412032;            // h double buf bf16 [2][B][H] = 1 MB
static constexpr size_t FLAG_OFF = 139460608;            // 256 block flags, 4 B dense
static constexpr size_t WS_NEED  = 139493376;

__device__ __forceinline__ unsigned short f2bf(float f) {
  union { float f; unsigned u; } v; v.f = f;
  unsigned r = v.u + 0x7fff + ((v.u >> 16) & 1);   // RNE
  return (unsigned short)(r >> 16);
}

__device__ __forceinline__ void cvt8(const float* __restrict__ s, unsigned short* __restrict__ d) {
  float4 a = *(const float4*)s;
  float4 b = *(const float4*)(s + 4);
  union { unsigned short us[8]; uint4 v; } o;
  o.us[0] = f2bf(a.x); o.us[1] = f2bf(a.y); o.us[2] = f2bf(a.z); o.us[3] = f2bf(a.w);
  o.us[4] = f2bf(b.x); o.us[5] = f2bf(b.y); o.us[6] = f2bf(b.z); o.us[7] = f2bf(b.w);
  *(uint4*)d = o.v;
}

// L2-bypassing h-fragment load: two 8-byte relaxed agent-scope atomic loads
// (sc1 -> served fresh from the coherent memory-side LLC; no buffer_inv).
__device__ __forceinline__ short8 ld_h(const unsigned short* p) {
  unsigned long long lo = __hip_atomic_load((unsigned long long*)(void*)p,
                                            __ATOMIC_RELAXED, __HIP_MEMORY_SCOPE_AGENT);
  unsigned long long hi = __hip_atomic_load((unsigned long long*)(void*)(p + 4),
                                            __ATOMIC_RELAXED, __HIP_MEMORY_SCOPE_AGENT);
  union { unsigned long long q[2]; short8 s; } u;
  u.q[0] = lo; u.q[1] = hi;
  return u.s;
}

__device__ __forceinline__ unsigned ld_flag(const unsigned* p) {
  return __hip_atomic_load((unsigned*)p, __ATOMIC_RELAXED, __HIP_MEMORY_SCOPE_AGENT);
}

// ---------------------------------------------------------------------------
// Init: x [B][T][I] fp32 -> xbf [T][B][I] bf16 ; W_ih fp32 -> bf16 ; zero h/flags
// ---------------------------------------------------------------------------
__global__ __launch_bounds__(256)
void init_kernel(const float* __restrict__ x, const float* __restrict__ Wi,
                 unsigned char* __restrict__ ws)
{
  unsigned short* xbf  = (unsigned short*)(ws + XBF_OFF);
  unsigned short* wibf = (unsigned short*)(ws + WIBF_OFF);
  const int bid = blockIdx.x;
  const int tid = threadIdx.x;

  if (bid < 32768) {
    const int rowid = bid * 4 + (tid >> 6);      // rowid = t*256 + b
    const int t = rowid >> 8;
    const int b = rowid & 255;
    const int i = (tid & 63) * 8;
    const float* src = x + ((size_t)b * Tsz + t) * Isz + i;
    unsigned short* dst = xbf + (size_t)rowid * Isz + i;
    cvt8(src, dst);
  } else if (bid < 32768 + 1024) {
    const size_t base = (size_t)(bid - 32768) * 2048 + (size_t)tid * 8;
    cvt8(Wi + base, wibf + base);
  } else {
    // zero h_buf (1 MB) + flags (32 KB) = 67584 x 16B chunks
    const int z = bid - 33792;                    // 0..259
    uint4 zero = make_uint4(0u, 0u, 0u, 0u);
    for (size_t j = (size_t)z * 256 + tid; j < 67584; j += (size_t)260 * 256)
      ((uint4*)(ws + HBUF_OFF))[j] = zero;
  }
}

// ---------------------------------------------------------------------------
// Persistent LSTM: 256 WGs x 512 threads (8 waves = 2/SIMD), K-split pairs.
// Sync v4 (anti poll-flood): per-BLOCK flags, 4 B dense (one rg's 64 flags =
// 4 cache lines). ONE poller wave per block (wv 7) lane-parallel polls them
// (fully coalesced) and posts per-K-half LDS go-words; the other 7 waves spin
// on LDS only -> fabric poll traffic drops >100x (was: 2048 waves x 64 lines
// every LLC round trip ~ 28 TB/s of line pressure congesting every sc1 RT).
// Producer: lower waves drain h stores (vmcnt0) + LDS done-count; wave 3
// publishes the block flag after observing count==4 (flag at LLC => data at
// LLC). h-load pipeline / K-split / reduction unchanged.
// ---------------------------------------------------------------------------
__global__ __launch_bounds__(512, 2)
void lstm_persistent(const float* __restrict__ Wh,
                     const float* __restrict__ b_ih, const float* __restrict__ b_hh,
                     const float* __restrict__ c0, float* __restrict__ out,
                     unsigned char* __restrict__ ws)
{
  const unsigned short* __restrict__ xbf  = (const unsigned short*)(ws + XBF_OFF);
  const unsigned short* __restrict__ wibf = (const unsigned short*)(ws + WIBF_OFF);
  unsigned short* __restrict__ hbuf = (unsigned short*)(ws + HBUF_OFF);
  unsigned* __restrict__ flags = (unsigned*)(ws + FLAG_OFF);

  __shared__ unsigned short WhT[64][1032];   // +8 pad: 2-way LDS aliasing (free)
  __shared__ float red[4][64][17];           // K-split partials; 17-pad: conflict-free
  __shared__ float bias[64];
  __shared__ unsigned go01[2];               // per-K-half go words (monotonic = t)
  __shared__ unsigned done_cnt;              // monotonic: 4 per step when slabs drained

  const int tid  = threadIdx.x;
  const int bid  = blockIdx.x;
  const int cg   = bid & 63;
  const int rg   = bid >> 6;
  const int wv    = tid >> 6;        // 0..7
  const int wv4   = wv & 3;          // row-slab index within block
  const int khalf = wv >> 2;         // 0: K 0..511, 1: K 512..1023
  const int lane = tid & 63;
  const int l16  = lane & 15;
  const int quad = lane >> 4;

  if (tid == 0) { go01[0] = 0; go01[1] = 0; done_cnt = 0; }

  // ---- stage W_hh slice (fp32 -> bf16) into LDS (512 threads) ----
  {
    const int n  = tid >> 3;                 // 0..63
    const int q  = n >> 4, u = n & 15;
    const int gc = q * 1024 + cg * 16 + u;
    const int k0 = (tid & 7) * 128;
    const float* src = Wh + (size_t)gc * Hsz + k0;
    unsigned short* dst = &WhT[n][k0];
    #pragma unroll 4
    for (int k = 0; k < 128; k += 8) cvt8(src + k, dst + k);
  }
  if (tid < 64) {
    const int q = tid >> 4, u = tid & 15;
    const int gc = q * 1024 + cg * 16 + u;
    bias[tid] = b_ih[gc] + b_hh[gc];
  }
  __syncthreads();

  const int rowbase = rg * 64 + wv4 * 16;
  const int arow    = rowbase + l16;
  const int hcol    = cg * 16 + l16;

  // block flags: flags[rg*64 + cg], 4 B dense -> 256 B per rg
  unsigned* const flagrow = flags + (size_t)rg * 64;
  unsigned* const myflag  = flagrow + cg;

  // loop-invariant biases in registers (lower waves only use them)
  const float bi_r = bias[l16];
  const float bf_r = bias[16 + l16];
  const float bg_r = bias[32 + l16];
  const float bo_r = bias[48 + l16];

  float creg[4] = {0.f, 0.f, 0.f, 0.f};
  if (khalf == 0) {
    #pragma unroll
    for (int r = 0; r < 4; ++r)
      creg[r] = c0[(size_t)(rowbase + quad * 4 + r) * Hsz + hcol];
  }

  const unsigned short* bp[4];
  #pragma unroll
  for (int q = 0; q < 4; ++q)
    bp[q] = wibf + (size_t)(q * 1024 + cg * 16 + l16) * Isz + khalf * 256 + quad * 8;

  int p = 0;
  for (int t = 0; t < Tsz; ++t) {
    const unsigned short* xt = xbf  + (size_t)t * Bsz * Isz + (size_t)arow * Isz
                                    + khalf * 256 + quad * 8;
    const unsigned short* hp = hbuf + (size_t)p * Bsz * Hsz + (size_t)arow * Hsz
                                    + khalf * 512 + quad * 8;
    const unsigned tgt = (unsigned)t;

    f32x4 acc[4];
    #pragma unroll
    for (int q = 0; q < 4; ++q) acc[q] = (f32x4){0.f, 0.f, 0.f, 0.f};

    // ---- x @ W_ih^T partial, this wave's K quarter (no h dependency) ----
    #pragma unroll
    for (int ks = 0; ks < 8; ++ks) {
      const int kk = ks * 32;
      short8 av = *(const short8*)(xt + kk);
      short8 b0 = *(const short8*)(bp[0] + kk);
      short8 b1 = *(const short8*)(bp[1] + kk);
      short8 b2 = *(const short8*)(bp[2] + kk);
      short8 b3 = *(const short8*)(bp[3] + kk);
      acc[0] = __builtin_amdgcn_mfma_f32_16x16x32_bf16(av, b0, acc[0], 0, 0, 0);
      acc[1] = __builtin_amdgcn_mfma_f32_16x16x32_bf16(av, b1, acc[1], 0, 0, 0);
      acc[2] = __builtin_amdgcn_mfma_f32_16x16x32_bf16(av, b2, acc[2], 0, 0, 0);
      acc[3] = __builtin_amdgcn_mfma_f32_16x16x32_bf16(av, b3, acc[3], 0, 0, 0);
    }

    // ---- hierarchical wait ----
    if (t > 0) {
      if (wv == 7) {
        // poller: one coalesced load covers this rg's 64 block flags (4 lines)
        unsigned done = 0;
        do {
          unsigned v = ld_flag(flagrow + lane);
          unsigned long long b = __ballot((int)(v >= tgt));
          if (!(done & 1u) && (unsigned)(b & 0xFFFFFFFFull) == 0xFFFFFFFFu) {
            if (lane == 0)
              __hip_atomic_store(&go01[0], tgt, __ATOMIC_RELAXED, __HIP_MEMORY_SCOPE_WORKGROUP);
            done |= 1u;
          }
          if (!(done & 2u) && (unsigned)(b >> 32) == 0xFFFFFFFFu) {
            if (lane == 0)
              __hip_atomic_store(&go01[1], tgt, __ATOMIC_RELAXED, __HIP_MEMORY_SCOPE_WORKGROUP);
            done |= 2u;
          }
        } while (done != 3u);
      } else {
        // workers: spin on LDS only (zero fabric traffic)
        while (__hip_atomic_load(&go01[khalf], __ATOMIC_RELAXED, __HIP_MEMORY_SCOPE_WORKGROUP) < tgt)
          ;
      }
      __atomic_signal_fence(__ATOMIC_SEQ_CST);   // keep data loads after observation
    }

    // ---- h @ W_hh^T over this wave's 512-col K half, depth-8 prefetch ----
    short8 hv[8];
    #pragma unroll
    for (int j = 0; j < 8; ++j) hv[j] = ld_h(hp + j * 32);

    const int kbase = khalf * 512;
    #pragma unroll
    for (int ks = 0; ks < 16; ++ks) {
      short8 av = hv[ks & 7];
      if (ks + 8 < 16) hv[ks & 7] = ld_h(hp + (ks + 8) * 32);
      const int kk = kbase + ks * 32;
      short8 b0 = *(const short8*)(&WhT[l16     ][kk + quad * 8]);
      short8 b1 = *(const short8*)(&WhT[16 + l16][kk + quad * 8]);
      short8 b2 = *(const short8*)(&WhT[32 + l16][kk + quad * 8]);
      short8 b3 = *(const short8*)(&WhT[48 + l16][kk + quad * 8]);
      acc[0] = __builtin_amdgcn_mfma_f32_16x16x32_bf16(av, b0, acc[0], 0, 0, 0);
      acc[1] = __builtin_amdgcn_mfma_f32_16x16x32_bf16(av, b1, acc[1], 0, 0, 0);
      acc[2] = __builtin_amdgcn_mfma_f32_16x16x32_bf16(av, b2, acc[2], 0, 0, 0);
      acc[3] = __builtin_amdgcn_mfma_f32_16x16x32_bf16(av, b3, acc[3], 0, 0, 0);
    }

    // ---- K-split reduction through LDS ----
    if (khalf) {
      #pragma unroll
      for (int q = 0; q < 4; ++q)
        #pragma unroll
        for (int r = 0; r < 4; ++r)
          red[wv4][lane][q * 4 + r] = acc[q][r];
    }
    __syncthreads();                       // barrier1: partials visible; all
                                           // waves' step-t h reads drained
    if (!khalf) {
      #pragma unroll
      for (int q = 0; q < 4; ++q)
        #pragma unroll
        for (int r = 0; r < 4; ++r)
          acc[q][r] += red[wv4][lane][q * 4 + r];
    }
    __syncthreads();                       // barrier2: red reusable next step

    if (!khalf) {
      // ---- epilogue: gates -> c,h; h published via sc1 (LLC) stores ----
      unsigned short* hn = hbuf + (size_t)(p ^ 1) * Bsz * Hsz;
      #pragma unroll
      for (int r = 0; r < 4; ++r) {
        float gi = acc[0][r] + bi_r;
        float gf = acc[1][r] + bf_r;
        float gg = acc[2][r] + bg_r;
        float go = acc[3][r] + bo_r;
        float si = 1.f / (1.f + __expf(-gi));
        float sf = 1.f / (1.f + __expf(-gf));
        float tg = 1.f - 2.f / (__expf(2.f * gg) + 1.f);
        float so = 1.f / (1.f + __expf(-go));
        float cn = sf * creg[r] + si * tg;
        creg[r] = cn;
        float tc = 1.f - 2.f / (__expf(2.f * cn) + 1.f);
        __hip_atomic_store(&hn[(size_t)(rowbase + quad * 4 + r) * Hsz + hcol],
                           f2bf(so * tc), __ATOMIC_RELAXED, __HIP_MEMORY_SCOPE_AGENT);
      }

      // ---- arrive: drain own sc1 stores (ACKed at LLC), mark LDS done;
      // slab-3 wave observes all 4 drains then publishes the block flag.
      // Flag store issues after the LDS observation (control dep), so flag
      // at LLC implies all of this block's h stores are at LLC. ----
      asm volatile("s_waitcnt vmcnt(0)" ::: "memory");
      if (lane == 0)
        __hip_atomic_fetch_add(&done_cnt, 1u, __ATOMIC_RELAXED, __HIP_MEMORY_SCOPE_WORKGROUP);
      if (wv4 == 3 && lane == 0) {
        while (__hip_atomic_load(&done_cnt, __ATOMIC_RELAXED, __HIP_MEMORY_SCOPE_WORKGROUP)
               < 4u * (tgt + 1u))
          ;
        __atomic_signal_fence(__ATOMIC_SEQ_CST);
        __hip_atomic_store(myflag, tgt + 1u, __ATOMIC_RELAXED, __HIP_MEMORY_SCOPE_AGENT);
      }
    }
    p ^= 1;
  }

  if (khalf == 0) {
    #pragma unroll
    for (int r = 0; r < 4; ++r)
      out[(size_t)(rowbase + quad * 4 + r) * Hsz + hcol] = creg[r];
  }
}

extern "C" void kernel_launch(void* const* d_in, const int* in_sizes, int n_in,
                              void* d_out, int out_size, void* d_ws, size_t ws_size,
                              hipStream_t stream) {
  const float* x   = (const float*)d_in[0];
  const float* Wi  = (const float*)d_in[1];
  const float* Wh  = (const float*)d_in[2];
  const float* bih = (const float*)d_in[3];
  const float* bhh = (const float*)d_in[4];
  const float* c0  = (const float*)d_in[5];
  float* out = (float*)d_out;
  unsigned char* ws = (unsigned char*)d_ws;

  if (ws_size < WS_NEED) return;

  init_kernel<<<34052, 256, 0, stream>>>(x, Wi, ws);

  void* args[] = { (void*)&Wh, (void*)&bih, (void*)&bhh,
                   (void*)&c0, (void*)&out, (void*)&ws };
  hipLaunchCooperativeKernel((void*)lstm_persistent, dim3(256), dim3(512),
                             args, 0, stream);
}